// Round 3
// baseline (62.259 us; speedup 1.0000x reference)
//
#include <hip/hip_runtime.h>
#include <hip/hip_bf16.h>

// GAT layer: out[b,i,j] = lrelu( (h@W@a1)[b,i] + (h@W@a2)[b,j] )
// B=4, N=4096, IN_F=256, OUT_F=64. Output: 4*4096*4096 fp32 = 256 MiB (write-bound).
// Algebraic collapse: e1 = h@(W@a1), e2 = h@(W@a2) — Wh never materialized.

#define B_DIM 4
#define N_DIM 4096
#define IN_F 256
#define OUT_F 64
#define SLOPE 0.2f

typedef float f32x4 __attribute__((ext_vector_type(4)));  // native vector: OK for nontemporal builtin

// Kernel 1 (fused): per block, compute v1/v2 = W@a1 / W@a2 into LDS, then
// 4 waves × 16 rows each: e1[row] = h_row.v1, e2[row] = h_row.v2.
// 256 blocks × 64 rows = 16384 rows. W re-read per block is L2-resident (64 KB).
__global__ void gat_dots(const float* __restrict__ h, const float* __restrict__ W,
                         const float* __restrict__ a,
                         float* __restrict__ e1, float* __restrict__ e2) {
    __shared__ float v1s[IN_F];
    __shared__ float v2s[IN_F];
    const int t = threadIdx.x;  // 0..255

    // phase 1: thread t computes v1[t], v2[t]
    {
        float s1 = 0.f, s2 = 0.f;
        const float* wr = W + t * OUT_F;
        #pragma unroll 8
        for (int j = 0; j < OUT_F; ++j) {
            float w = wr[j];
            s1 += w * a[j];
            s2 += w * a[OUT_F + j];
        }
        v1s[t] = s1;
        v2s[t] = s2;
    }
    __syncthreads();

    // phase 2: each wave handles 16 rows
    const int lane = t & 63;
    const int wid  = t >> 6;
    const f32x4 v1 = reinterpret_cast<const f32x4*>(v1s)[lane];
    const f32x4 v2 = reinterpret_cast<const f32x4*>(v2s)[lane];
    const int base = blockIdx.x * 64 + wid * 16;

    for (int r = 0; r < 16; ++r) {
        const int row = base + r;
        const f32x4 hv = reinterpret_cast<const f32x4*>(h + (size_t)row * IN_F)[lane];
        float d1 = hv.x * v1.x + hv.y * v1.y + hv.z * v1.z + hv.w * v1.w;
        float d2 = hv.x * v2.x + hv.y * v2.y + hv.z * v2.z + hv.w * v2.w;
        #pragma unroll
        for (int m = 32; m >= 1; m >>= 1) {
            d1 += __shfl_xor(d1, m);
            d2 += __shfl_xor(d2, m);
        }
        if (lane == 0) {
            e1[row] = d1;
            e2[row] = d2;
        }
    }
}

// Kernel 2: epilogue. One block per output row (16384 blocks).
// e1[row] hoisted (uniform); e2 row of this batch is L1/L2-resident;
// nontemporal dwordx4 stores stream 256 MiB without polluting L2.
__global__ void gat_epilogue(const float* __restrict__ e1, const float* __restrict__ e2,
                             float* __restrict__ out) {
    const int row = blockIdx.x;            // b*N + i
    const int b   = row >> 12;             // row / 4096
    const float s = e1[row];
    const f32x4* e2v = reinterpret_cast<const f32x4*>(e2 + b * N_DIM);
    f32x4* outv = reinterpret_cast<f32x4*>(out + (size_t)row * N_DIM);

    #pragma unroll
    for (int k = 0; k < 4; ++k) {
        const int c = threadIdx.x + k * 256;
        const f32x4 t = e2v[c];
        f32x4 o;
        float ex = s + t.x; o.x = fmaxf(ex, SLOPE * ex);
        float ey = s + t.y; o.y = fmaxf(ey, SLOPE * ey);
        float ez = s + t.z; o.z = fmaxf(ez, SLOPE * ez);
        float ew = s + t.w; o.w = fmaxf(ew, SLOPE * ew);
        __builtin_nontemporal_store(o, &outv[c]);
    }
}

extern "C" void kernel_launch(void* const* d_in, const int* in_sizes, int n_in,
                              void* d_out, int out_size, void* d_ws, size_t ws_size,
                              hipStream_t stream) {
    const float* h = (const float*)d_in[0];   // 4*4096*256
    const float* W = (const float*)d_in[1];   // 256*64
    const float* a = (const float*)d_in[2];   // 128

    float* ws = (float*)d_ws;
    float* e1 = ws;                    // 16384 floats
    float* e2 = ws + 16384;            // 16384 floats

    gat_dots<<<256, 256, 0, stream>>>(h, W, a, e1, e2);
    gat_epilogue<<<B_DIM * N_DIM, 256, 0, stream>>>(e1, e2, (float*)d_out);
}

// Round 4
// 60.394 us; speedup vs baseline: 1.0309x; 1.0309x over previous
//
#include <hip/hip_runtime.h>
#include <hip/hip_bf16.h>

// GAT layer: out[b,i,j] = lrelu( (h@W@a1)[b,i] + (h@W@a2)[b,j] )
// B=4, N=4096, IN_F=256, OUT_F=64. Output: 4*4096*4096 fp32 = 256 MiB (write-bound).
// Algebraic collapse: e1 = h@(W@a1), e2 = h@(W@a2) — Wh never materialized.

#define B_DIM 4
#define N_DIM 4096
#define IN_F 256
#define OUT_F 64
#define SLOPE 0.2f

typedef float f32x4 __attribute__((ext_vector_type(4)));

// K1: fused v + dots. 1024 blocks x 256 threads.
// Phase 1: thread t computes v1[t],v2[t] = W[t,:]@a1, W[t,:]@a2 into LDS.
// Phase 2: 4 waves x 4 rows each (wave-per-row butterfly) -> e1,e2. 1024*16 = 16384 rows.
__global__ void gat_dots(const float* __restrict__ h, const float* __restrict__ W,
                         const float* __restrict__ a,
                         float* __restrict__ e1, float* __restrict__ e2) {
    __shared__ float v1s[IN_F];
    __shared__ float v2s[IN_F];
    const int t = threadIdx.x;

    {
        float s1 = 0.f, s2 = 0.f;
        const float* wr = W + t * OUT_F;
        #pragma unroll 8
        for (int j = 0; j < OUT_F; ++j) {
            float w = wr[j];
            s1 += w * a[j];          // a[j] uniform -> scalar load
            s2 += w * a[OUT_F + j];
        }
        v1s[t] = s1;
        v2s[t] = s2;
    }
    __syncthreads();

    const int lane = t & 63;
    const int wid  = t >> 6;
    const f32x4 v1 = reinterpret_cast<const f32x4*>(v1s)[lane];
    const f32x4 v2 = reinterpret_cast<const f32x4*>(v2s)[lane];
    const int base = blockIdx.x * 16 + wid * 4;

    #pragma unroll
    for (int r = 0; r < 4; ++r) {
        const int row = base + r;
        const f32x4 hv = reinterpret_cast<const f32x4*>(h + (size_t)row * IN_F)[lane];
        float d1 = hv.x * v1.x + hv.y * v1.y + hv.z * v1.z + hv.w * v1.w;
        float d2 = hv.x * v2.x + hv.y * v2.y + hv.z * v2.z + hv.w * v2.w;
        #pragma unroll
        for (int m = 32; m >= 1; m >>= 1) {
            d1 += __shfl_xor(d1, m);
            d2 += __shfl_xor(d2, m);
        }
        if (lane == 0) {
            e1[row] = d1;
            e2[row] = d2;
        }
    }
}

// K2: epilogue. 2048 blocks x 256 threads, 8 rows per block (all in one batch:
// 8 | 4096). e2 row chunk held in 16 registers, loaded ONCE per block -> read
// traffic 16x lower than block-per-row (avoids L2 thrash vs the write stream).
// Plain dwordx4 stores (fill kernel proves ~7 TB/s without NT).
__global__ void gat_epilogue(const float* __restrict__ e1, const float* __restrict__ e2,
                             float* __restrict__ out) {
    const int rowBase = blockIdx.x * 8;        // b*N + i base
    const int b       = rowBase >> 12;
    const int tid     = threadIdx.x;

    const f32x4* e2v = reinterpret_cast<const f32x4*>(e2 + b * N_DIM);
    const f32x4 c0 = e2v[tid];
    const f32x4 c1 = e2v[tid + 256];
    const f32x4 c2 = e2v[tid + 512];
    const f32x4 c3 = e2v[tid + 768];

    for (int r = 0; r < 8; ++r) {
        const int row = rowBase + r;
        const float s = e1[row];               // uniform -> scalar load
        f32x4* outv = reinterpret_cast<f32x4*>(out + (size_t)row * N_DIM);
        f32x4 o0, o1, o2, o3;
        #define LRELU(dst, src) { \
            float ex = s + (src).x; (dst).x = fmaxf(ex, SLOPE * ex); \
            float ey = s + (src).y; (dst).y = fmaxf(ey, SLOPE * ey); \
            float ez = s + (src).z; (dst).z = fmaxf(ez, SLOPE * ez); \
            float ew = s + (src).w; (dst).w = fmaxf(ew, SLOPE * ew); }
        LRELU(o0, c0) LRELU(o1, c1) LRELU(o2, c2) LRELU(o3, c3)
        #undef LRELU
        outv[tid]       = o0;
        outv[tid + 256] = o1;
        outv[tid + 512] = o2;
        outv[tid + 768] = o3;
    }
}

extern "C" void kernel_launch(void* const* d_in, const int* in_sizes, int n_in,
                              void* d_out, int out_size, void* d_ws, size_t ws_size,
                              hipStream_t stream) {
    const float* h = (const float*)d_in[0];   // 4*4096*256
    const float* W = (const float*)d_in[1];   // 256*64
    const float* a = (const float*)d_in[2];   // 128

    float* ws = (float*)d_ws;
    float* e1 = ws;                    // 16384 floats
    float* e2 = ws + 16384;            // 16384 floats

    gat_dots<<<1024, 256, 0, stream>>>(h, W, a, e1, e2);
    gat_epilogue<<<2048, 256, 0, stream>>>(e1, e2, (float*)d_out);
}